// Round 7
// baseline (462.499 us; speedup 1.0000x reference)
//
#include <hip/hip_runtime.h>
#include <hip/hip_bf16.h>
#include <math.h>

// Flash attention fwd, B=32, LQ=LK=2048, D=128, fp32 in/out, per-batch valid_len mask.
// Swapped QK^T (S^T = mfma(K,Q)): lane owns a q-row -> lane-local softmax; PV as
// mfma(A=V^T-frag, B=P-frag).
// R7: KV-split occupancy fix. 512-thr blocks: waves 0-3 (group A) process even KV
// tiles, waves 4-7 (group B) odd tiles, same 128 q-rows, own 32KB single-buffer each
// -> 16 waves/CU (4/SIMD) vs 8 before. Per-group (m,l,acc); flash-merge via LDS at
// end. R6's T14/setprio reverted (regressed 128->142us; convert-at-LOAD restored).

#define BATCH 32
#define SEQL  2048
#define DIM   128
#define KVB   64
#define QTILE 128
#define KBUF  16384
#define GBUF  32768
#define MLOFF 65536
#define EPSTR 34

typedef __attribute__((ext_vector_type(8)))  __bf16 bf8;
typedef __attribute__((ext_vector_type(16))) float  f16v;
typedef __attribute__((ext_vector_type(2)))  unsigned int u32x2;
typedef unsigned int u32;

static __device__ __forceinline__ f16v mfma32(bf8 a, bf8 b, f16v c) {
  return __builtin_amdgcn_mfma_f32_32x32x16_bf16(a, b, c, 0, 0, 0);
}
static __device__ __forceinline__ u32 cvtpk(float lo, float hi) {
  u32 r; asm("v_cvt_pk_bf16_f32 %0, %1, %2" : "=v"(r) : "v"(lo), "v"(hi)); return r;
}
static __device__ __forceinline__ void plswap(u32& a, u32& b) {
#if __has_builtin(__builtin_amdgcn_permlane32_swap)
  auto r = __builtin_amdgcn_permlane32_swap(a, b, false, false);
  a = (u32)r[0]; b = (u32)r[1];
#else
  asm("s_nop 1\n\tv_permlane32_swap_b32 %0, %1" : "+v"(a), "+v"(b));
#endif
}
static __device__ __forceinline__ float xmax(float x) {
  u32 a = __builtin_bit_cast(u32, x), c = a;
  plswap(a, c);
  return fmaxf(__builtin_bit_cast(float, a), __builtin_bit_cast(float, c));
}
static __device__ __forceinline__ float xadd(float x) {
  u32 a = __builtin_bit_cast(u32, x), c = a;
  plswap(a, c);
  return __builtin_bit_cast(float, a) + __builtin_bit_cast(float, c);
}
static __device__ __forceinline__ float fexp2(float x) {
#if __has_builtin(__builtin_amdgcn_exp2f)
  return __builtin_amdgcn_exp2f(x);
#else
  return exp2f(x);
#endif
}
static __device__ __forceinline__ u32 ext16(u32x2 v, int c) {
  u32 w = ((c >> 1) & 1) ? v[1] : v[0];
  return (c & 1) ? (w >> 16) : (w & 0xffffu);
}

// build one PV B-frag (16 kv x 32 q) from 8 in-lane P values (T12 recipe)
#define MKPB(ARR, BASE, DST) {                                   \
    u32 x0 = cvtpk(ARR[BASE+0], ARR[BASE+1]);                    \
    u32 y0 = cvtpk(ARR[BASE+4], ARR[BASE+5]);                    \
    plswap(x0, y0);                                              \
    u32 x1 = cvtpk(ARR[BASE+2], ARR[BASE+3]);                    \
    u32 y1 = cvtpk(ARR[BASE+6], ARR[BASE+7]);                    \
    plswap(x1, y1);                                              \
    union { u32 u[4]; bf8 v; } uu;                               \
    uu.u[0] = x0; uu.u[1] = x1; uu.u[2] = y0; uu.u[3] = y1;      \
    DST = uu.v; }

__global__ __launch_bounds__(512, 4)
void attn_fwd(const float* __restrict__ Q, const float* __restrict__ K,
              const float* __restrict__ V, const int* __restrict__ vlen,
              float* __restrict__ O)
{
  __shared__ __align__(128) char smem[MLOFF + 1024];   // 2 group-bufs (64KB) + ml

  const int tid  = threadIdx.x;
  const int w    = tid >> 6;        // 0..7
  const int gidx = w >> 2;          // group: 0 = even tiles, 1 = odd tiles
  const int wl   = w & 3;           // wave-in-group -> q sub-block
  const int lane = tid & 63;
  const int ql   = lane & 31;
  const int hi   = lane >> 5;
  const int twg  = (tid >> 5) & 7;  // 0..7 within group (staging row)
  const int d4   = tid & 31;

  // XCD-aware decode: XCD x gets batches 4x..4x+3 entirely (K/V L2 locality)
  const int fid  = blockIdx.x;
  const int bb   = (fid & 7) * 4 + ((fid >> 3) >> 4);
  const int q0   = ((fid >> 3) & 15) * QTILE;

  const int valid = vlen[bb];
  const int nt    = (valid + KVB - 1) / KVB;
  const int S     = (nt + 1) >> 1;          // barrier periods (tiles per group)

  const float QS = 0.08838834764831845f * 1.4426950408889634f;

  // ---- Q B-fragments: lane holds Q[q0+wl*32+ql][kb*16 + hi*8 + e]
  bf8 qf[8];
  {
    const float* qp = Q + ((size_t)bb * SEQL + q0 + wl*32 + ql) * DIM + hi*8;
    #pragma unroll
    for (int kb = 0; kb < 8; ++kb) {
      float4 a = *(const float4*)(qp + kb*16);
      float4 c = *(const float4*)(qp + kb*16 + 4);
      union { u32 u[4]; bf8 v; } t;
      t.u[0] = cvtpk(a.x*QS, a.y*QS);
      t.u[1] = cvtpk(a.z*QS, a.w*QS);
      t.u[2] = cvtpk(c.x*QS, c.y*QS);
      t.u[3] = cvtpk(c.z*QS, c.w*QS);
      qf[kb] = t.v;
    }
  }

  f16v acc[4] = {};
  float m = -INFINITY, l = 0.f;

  // staging registers (bf16-converted at load; R5-proven)
  u32x2 kreg[8], vA[4], vB[4];
  const float* Kb = K + ((size_t)bb * SEQL) * DIM;
  const float* Vb = V + ((size_t)bb * SEQL) * DIM;

  char* const kbuf = smem + gidx * GBUF;        // this group's K tile
  char* const vbuf = kbuf + KBUF;               // this group's V^T tile

  auto LOAD = [&](int t) {
    const int kv0 = t * KVB;
    #pragma unroll
    for (int i = 0; i < 8; ++i) {
      float4 x = *(const float4*)(Kb + (size_t)(kv0 + i*8 + twg) * DIM + d4*4);
      kreg[i][0] = cvtpk(x.x, x.y); kreg[i][1] = cvtpk(x.z, x.w);
    }
    #pragma unroll
    for (int i = 0; i < 4; ++i) {
      const int kvA = kv0 + 16*i + 2*twg;
      float4 x = *(const float4*)(Vb + (size_t)kvA * DIM + d4*4);
      float4 y = *(const float4*)(Vb + (size_t)(kvA + 1) * DIM + d4*4);
      vA[i][0] = cvtpk(x.x, x.y); vA[i][1] = cvtpk(x.z, x.w);
      vB[i][0] = cvtpk(y.x, y.y); vB[i][1] = cvtpk(y.z, y.w);
    }
  };

  const int kwb = twg*256 + ((d4*8) ^ (twg << 4));  // K LDS write offset (swizzled)
  auto STORE = [&]() {
    #pragma unroll
    for (int i = 0; i < 8; ++i)
      *(u32x2*)(kbuf + i*2048 + kwb) = kreg[i];
    #pragma unroll
    for (int i = 0; i < 4; ++i) {
      const int p = 8*i + twg;           // kv pair index 0..31, kv = {2p, 2p+1}
      #pragma unroll
      for (int j = 0; j < 4; ++j) {
        const int c   = (j + (d4 >> 2)) & 3;   // row-phase rotation (bank spread)
        const int row = 4*d4 + c;              // Vt row = d
        u32 val = ext16(vA[i], c) | (ext16(vB[i], c) << 16);
        *(u32*)(vbuf + row*128 + ((4*p) ^ ((row & 7) << 4))) = val;
      }
    }
  };

  if (gidx < nt) { LOAD(gidx); STORE(); }   // group B inactive iff nt==1
  __syncthreads();

  for (int s = 0; s < S; ++s) {
    const int  t   = gidx + 2*s;
    const bool act = t < nt;
    const bool nxt = t + 2 < nt;

    if (act) {
      if (nxt) LOAD(t + 2);            // issue next own-tile loads (hidden by compute)

      // ---- S^T = K Q^T : two 32-kv tiles, acc col = q (lane&31), row = kv
      f16v s0v = {}, s1v = {};
      {
        const int rb = ql * 256;
        #pragma unroll
        for (int kb = 0; kb < 8; ++kb) {
          const int off = rb + (((kb << 5) | (hi << 4)) ^ ((ql & 7) << 4));
          bf8 k0 = *(const bf8*)(kbuf + off);
          bf8 k1 = *(const bf8*)(kbuf + off + 8192);   // +32 kv rows
          s0v = mfma32(k0, qf[kb], s0v);
          s1v = mfma32(k1, qf[kb], s1v);
        }
      }

      const int kv0 = t * KVB;
      if (kv0 + KVB > valid) {         // boundary tile mask
        #pragma unroll
        for (int r = 0; r < 16; ++r) {
          const int kvl = (r & 3) + 8*(r >> 2) + 4*hi;
          if (kv0 + kvl >= valid)      s0v[r] = -INFINITY;
          if (kv0 + 32 + kvl >= valid) s1v[r] = -INFINITY;
        }
      }

      // ---- lane-local online softmax
      float c0 = fmaxf(s0v[0], s1v[0]);
      float c1 = fmaxf(s0v[1], s1v[1]);
      float c2 = fmaxf(s0v[2], s1v[2]);
      float c3 = fmaxf(s0v[3], s1v[3]);
      #pragma unroll
      for (int r = 4; r < 16; r += 4) {
        c0 = fmaxf(c0, fmaxf(s0v[r],     s1v[r]));
        c1 = fmaxf(c1, fmaxf(s0v[r + 1], s1v[r + 1]));
        c2 = fmaxf(c2, fmaxf(s0v[r + 2], s1v[r + 2]));
        c3 = fmaxf(c3, fmaxf(s0v[r + 3], s1v[r + 3]));
      }
      const float tmax = xmax(fmaxf(fmaxf(c0, c1), fmaxf(c2, c3)));

      if (!__all(tmax <= m + 8.0f)) {  // defer-max (T13)
        const float mn = fmaxf(m, tmax);
        const float al = fexp2(m - mn);
        #pragma unroll
        for (int d = 0; d < 4; ++d) acc[d] *= al;
        l *= al;
        m = mn;
      }

      float p0[16], p1[16];
      #pragma unroll
      for (int r = 0; r < 16; ++r) {
        p0[r] = fexp2(s0v[r] - m);
        p1[r] = fexp2(s1v[r] - m);
      }
      {
        float d0 = p0[0] + p1[0], d1 = p0[1] + p1[1];
        float d2 = p0[2] + p1[2], d3 = p0[3] + p1[3];
        #pragma unroll
        for (int r = 4; r < 16; r += 4) {
          d0 += p0[r]     + p1[r];
          d1 += p0[r + 1] + p1[r + 1];
          d2 += p0[r + 2] + p1[r + 2];
          d3 += p0[r + 3] + p1[r + 3];
        }
        l += xadd((d0 + d1) + (d2 + d3));
      }

      // ---- P -> bf16 B-frags in-register
      bf8 pb[4];
      MKPB(p0, 0, pb[0]); MKPB(p0, 8, pb[1]);
      MKPB(p1, 0, pb[2]); MKPB(p1, 8, pb[3]);

      // ---- O^T += V^T P
      #pragma unroll
      for (int db = 0; db < 4; ++db) {
        #pragma unroll
        for (int ks = 0; ks < 4; ++ks) {
          const int off = (db*32 + ql)*128 + (((ks << 5) | (hi << 4)) ^ ((ql & 7) << 4));
          bf8 vf = *(const bf8*)(vbuf + off);
          acc[db] = mfma32(vf, pb[ks], acc[db]);
        }
      }
    }

    __syncthreads();                   // all readers of both group-bufs done
    if (nxt) STORE();                  // overwrite own buffer with tile t+2
    __syncthreads();
  }

  // ---- flash-merge group B partials into group A, then store
  if (gidx == 1) {                     // publish B partials
    float* pr = (float*)(smem + wl * KBUF);
    #pragma unroll
    for (int db = 0; db < 4; ++db) {
      #pragma unroll
      for (int r = 0; r < 16; ++r) {
        const int dloc = (r & 3) + 8*(r >> 2) + 4*hi;
        pr[(db*32 + dloc)*32 + ql] = acc[db][r];
      }
    }
    if (hi == 0)
      ((float2*)(smem + MLOFF))[wl*32 + ql] = make_float2(m, l);
  }
  __syncthreads();
  if (gidx == 0) {                     // combine (reads only; regs updated in place)
    const float2 ml2 = ((const float2*)(smem + MLOFF))[wl*32 + ql];
    const float mf = fmaxf(m, ml2.x);
    const float w1 = fexp2(m - mf);
    const float w2 = fexp2(ml2.x - mf);
    const float* pr = (const float*)(smem + wl * KBUF);
    #pragma unroll
    for (int db = 0; db < 4; ++db) {
      #pragma unroll
      for (int r = 0; r < 16; ++r) {
        const int dloc = (r & 3) + 8*(r >> 2) + 4*hi;
        acc[db][r] = acc[db][r]*w1 + pr[(db*32 + dloc)*32 + ql]*w2;
      }
    }
    l = l*w1 + ml2.y*w2;
  }
  __syncthreads();                     // all combine-reads done before ep overwrites

  if (gidx == 0) {                     // normalize, transpose via LDS, coalesced store
    const float invl = 1.0f / l;
    float* ep = (float*)smem + (size_t)wl * (32 * EPSTR);
    const size_t orow0 = (size_t)bb * SEQL + q0 + wl*32;
    #pragma unroll
    for (int db = 0; db < 4; ++db) {
      #pragma unroll
      for (int r = 0; r < 16; ++r) {
        const int dloc = (r & 3) + 8*(r >> 2) + 4*hi;
        ep[ql*EPSTR + dloc] = acc[db][r] * invl;
      }
      #pragma unroll
      for (int pq = 0; pq < 4; ++pq) {
        const int qr = (lane >> 3) + pq*8;
        const float* rp = ep + qr*EPSTR + (lane & 7)*4;
        float2 x0 = *(const float2*)rp;
        float2 x1 = *(const float2*)(rp + 2);
        float4 st = make_float4(x0.x, x0.y, x1.x, x1.y);
        *(float4*)(O + (orow0 + qr)*DIM + db*32 + (lane & 7)*4) = st;
      }
    }
  }
}

extern "C" void kernel_launch(void* const* d_in, const int* in_sizes, int n_in,
                              void* d_out, int out_size, void* d_ws, size_t ws_size,
                              hipStream_t stream) {
  const float* Q  = (const float*)d_in[0];
  const float* K  = (const float*)d_in[1];
  const float* V  = (const float*)d_in[2];
  const int*   vl = (const int*)d_in[3];
  float* O = (float*)d_out;
  attn_fwd<<<dim3(512), dim3(512), 0, stream>>>(Q, K, V, vl, O);
}